// Round 1
// baseline (326.911 us; speedup 1.0000x reference)
//
#include <hip/hip_runtime.h>

typedef unsigned int uint;
typedef unsigned short ushort;
typedef __attribute__((ext_vector_type(8))) short short8;
typedef __attribute__((ext_vector_type(4))) float f32x4;
typedef __attribute__((ext_vector_type(4))) uint uint4w;

#define T_LEN 32768
#define EMB 300
#define HID 256
#define NCOLS 4096

__device__ __forceinline__ ushort f2bf(float f) {
  uint u = __float_as_uint(f);
  return (ushort)((u + 0x7fffu + ((u >> 16) & 1u)) >> 16);
}
__device__ __forceinline__ float bf2f(ushort u) {
  return __uint_as_float(((uint)u) << 16);
}
__device__ __forceinline__ float sigm(float x) { return 1.f / (1.f + __expf(-x)); }
__device__ __forceinline__ float tanh_(float x) { return 2.f / (1.f + __expf(-2.f * x)) - 1.f; }

__device__ __forceinline__ void gload_lds16(const void* g, void* l) {
  __builtin_amdgcn_global_load_lds((const __attribute__((address_space(1))) void*)g,
                                   (__attribute__((address_space(3))) void*)l, 16, 0, 0);
}

// ---------------- prep: bf16 conversions + embedding gather ----------------
__global__ void prep_kernel(const float* __restrict__ emb,
                            const float* __restrict__ wihf, const float* __restrict__ whhf,
                            const float* __restrict__ bihf, const float* __restrict__ bhhf,
                            const float* __restrict__ wihb, const float* __restrict__ whhb,
                            const float* __restrict__ bihb, const float* __restrict__ bhhb,
                            const int* __restrict__ seq,
                            ushort* __restrict__ X, ushort* __restrict__ Wih,
                            ushort* __restrict__ Whh, float* __restrict__ bias) {
  const int NX = T_LEN * 40;      // 32768 rows x 40 groups of 8 k (K padded to 320)
  const int NWIH = 2048 * 40;
  const int NWHH = 2048 * 32;
  const int NB = 2048;
  const int total = NX + NWIH + NWHH + NB;
  for (int t = blockIdx.x * blockDim.x + threadIdx.x; t < total; t += gridDim.x * blockDim.x) {
    if (t < NX) {
      int r = t / 40, k8 = t % 40, k = k8 * 8;
      int col = r >> 3, j = r & 7;
      int tok = (col == 0) ? j : (col * 8 - 1 + j);   // matches reference idx (no clipping hit)
      const float* src = emb + (long)seq[tok] * EMB + k;
      alignas(16) ushort tmp[8];
#pragma unroll
      for (int i = 0; i < 8; ++i) tmp[i] = (k + i < EMB) ? f2bf(src[i]) : (ushort)0;
      *(uint4w*)(X + (long)r * 320 + k) = *(const uint4w*)tmp;
    } else if (t < NX + NWIH) {
      int t2 = t - NX;
      int n = t2 / 40, k8 = t2 % 40, k = k8 * 8;
      const float* src = ((n < 1024) ? wihf : wihb) + (long)(n & 1023) * EMB + k;
      alignas(16) ushort tmp[8];
#pragma unroll
      for (int i = 0; i < 8; ++i) tmp[i] = (k + i < EMB) ? f2bf(src[i]) : (ushort)0;
      *(uint4w*)(Wih + (long)n * 320 + k) = *(const uint4w*)tmp;
    } else if (t < NX + NWIH + NWHH) {
      int t3 = t - NX - NWIH;
      int n = t3 / 32, k8 = t3 % 32, k = k8 * 8;
      const float* src = ((n < 1024) ? whhf : whhb) + (long)(n & 1023) * HID + k;
      alignas(16) ushort tmp[8];
#pragma unroll
      for (int i = 0; i < 8; ++i) tmp[i] = f2bf(src[i]);
      *(uint4w*)(Whh + (long)n * 256 + k) = *(const uint4w*)tmp;
    } else {
      int n = t - NX - NWIH - NWHH;
      bias[n] = (n < 1024) ? (bihf[n] + bhhf[n]) : (bihb[n - 1024] + bhhb[n - 1024]);
    }
  }
}

// ---------------- K1: xg = X @ Wih^T + bias  (M=32768,K=320,N=2048) ----------------
__global__ void gemm_xg_kernel(const ushort* __restrict__ X, const ushort* __restrict__ Wih,
                               const float* __restrict__ bias, ushort* __restrict__ xg) {
  __shared__ ushort a_lds[2][128 * 32];
  const int tid = threadIdx.x;
  const int lane = tid & 63, w = tid >> 6;
  const int wr = w >> 1, wc = w & 1;
  const int qrow = lane >> 4, ln = lane & 15;
  const int m0 = blockIdx.x * 128, n0 = blockIdx.y * 128;

  auto stage = [&](int buf, int kt) {
#pragma unroll
    for (int q = 0; q < 2; ++q) {
      int byteoff = w * 2048 + q * 1024 + lane * 16;
      int row = byteoff >> 6, koff = byteoff & 63;
      const char* src = (const char*)X + (long)(m0 + row) * 640 + kt * 64 + koff;
      void* dst = (char*)&a_lds[buf][0] + w * 2048 + q * 1024;  // wave-uniform base
      gload_lds16(src, dst);
    }
  };

  const f32x4 fzero = {0.f, 0.f, 0.f, 0.f};
  f32x4 acc[4][4];
#pragma unroll
  for (int i = 0; i < 4; ++i)
#pragma unroll
    for (int jj = 0; jj < 4; ++jj) acc[i][jj] = fzero;

  stage(0, 0);
#pragma unroll 1
  for (int kt = 0; kt < 10; ++kt) {
    asm volatile("s_waitcnt vmcnt(0)" ::: "memory");
    __syncthreads();
    if (kt < 9) stage((kt + 1) & 1, kt + 1);
    const int buf = kt & 1;
    short8 a[4], b[4];
#pragma unroll
    for (int rt = 0; rt < 4; ++rt)
      a[rt] = *(const short8*)&a_lds[buf][(wr * 64 + rt * 16 + ln) * 32 + qrow * 8];
#pragma unroll
    for (int nt = 0; nt < 4; ++nt)
      b[nt] = *(const short8*)(Wih + (long)(n0 + wc * 64 + nt * 16 + ln) * 320 + kt * 32 + qrow * 8);
#pragma unroll
    for (int rt = 0; rt < 4; ++rt)
#pragma unroll
      for (int nt = 0; nt < 4; ++nt)
        acc[rt][nt] = __builtin_amdgcn_mfma_f32_16x16x32_bf16(a[rt], b[nt], acc[rt][nt], 0, 0, 0);
  }

#pragma unroll
  for (int nt = 0; nt < 4; ++nt) {
    int n = n0 + wc * 64 + nt * 16 + ln;
    float bv = bias[n];
#pragma unroll
    for (int rt = 0; rt < 4; ++rt) {
      int rowb = m0 + wr * 64 + rt * 16 + qrow * 4;
#pragma unroll
      for (int r = 0; r < 4; ++r)
        xg[(long)(rowb + r) * 2048 + n] = f2bf(acc[rt][nt][r] + bv);
    }
  }
}

// ---------------- K2: fused masked LSTM recurrence, one direction per block ----------------
// grid 256 = {d in 0..1} x {cg in 0..127}; 32 columns per block; 512 threads (8 waves)
__global__ void lstm_kernel(const ushort* __restrict__ xg, const ushort* __restrict__ Whh,
                            float* __restrict__ out) {
  __shared__ ushort h_lds[32][264];       // [col][hid], padded to kill bank conflicts
  __shared__ ushort xg_lds[32][1024];     // [col][gate*256+hid] for this dir, this step
  const int tid = threadIdx.x;
  const int lane = tid & 63, w = tid >> 6;   // w = hid-slice owner (32 hid per wave)
  const int qrow = lane >> 4, ln = lane & 15;
  const int bid = blockIdx.x;
  const int d = bid >> 7, cg = bid & 127;

  for (int i = tid; i < 32 * 264 / 2; i += 512) ((uint*)h_lds)[i] = 0u;

  float c_st[2][2][4], h_st[2][2][4];
#pragma unroll
  for (int rt = 0; rt < 2; ++rt)
#pragma unroll
    for (int q = 0; q < 2; ++q)
#pragma unroll
      for (int r = 0; r < 4; ++r) { c_st[rt][q][r] = 0.f; h_st[rt][q][r] = 0.f; }

  const f32x4 fzero = {0.f, 0.f, 0.f, 0.f};

#pragma unroll 1
  for (int it = 0; it < 8; ++it) {
    const int j = d ? (7 - it) : it;
    __syncthreads();  // prev iter's xg_lds reads + h_lds writes done
    // stage this step's xg tile: 32 cols x 1024 gates (this dir) = 64 KB
#pragma unroll
    for (int q = 0; q < 8; ++q) {
      int byteoff = w * 8192 + q * 1024 + lane * 16;
      int cloc = byteoff >> 11, noff = byteoff & 2047;
      const char* src = (const char*)xg + (long)((cg * 32 + cloc) * 8 + j) * 4096 + d * 2048 + noff;
      void* dst = (char*)&xg_lds[0][0] + w * 8192 + q * 1024;  // wave-uniform base
      gload_lds16(src, dst);
    }
    asm volatile("s_waitcnt vmcnt(0)" ::: "memory");
    __syncthreads();

    f32x4 acc[4][2][2];  // [gate][q(hid-16-block)][row-tile]
#pragma unroll
    for (int g = 0; g < 4; ++g)
#pragma unroll
      for (int q = 0; q < 2; ++q)
#pragma unroll
        for (int rt = 0; rt < 2; ++rt) acc[g][q][rt] = fzero;

    if (it > 0) {  // h==0 at it==0, skip GEMM
#pragma unroll
      for (int ks = 0; ks < 8; ++ks) {
        short8 a0 = *(const short8*)&h_lds[ln][ks * 32 + qrow * 8];
        short8 a1 = *(const short8*)&h_lds[16 + ln][ks * 32 + qrow * 8];
#pragma unroll
        for (int g = 0; g < 4; ++g)
#pragma unroll
          for (int q = 0; q < 2; ++q) {
            short8 b = *(const short8*)(Whh +
                (long)(d * 1024 + g * 256 + w * 32 + q * 16 + ln) * 256 + ks * 32 + qrow * 8);
            acc[g][q][0] = __builtin_amdgcn_mfma_f32_16x16x32_bf16(a0, b, acc[g][q][0], 0, 0, 0);
            acc[g][q][1] = __builtin_amdgcn_mfma_f32_16x16x32_bf16(a1, b, acc[g][q][1], 0, 0, 0);
          }
      }
    }
    __syncthreads();  // GEMM's h_lds reads done before overwriting h_lds

    // each lane holds all 4 gates for its 16 cells: (cc = rt*16+qrow*4+r, hid = w*32+q*16+ln)
    const bool mstep = d ? (it == 0) : (it == 7);
#pragma unroll
    for (int rt = 0; rt < 2; ++rt)
#pragma unroll
      for (int q = 0; q < 2; ++q)
#pragma unroll
        for (int r = 0; r < 4; ++r) {
          int cc = rt * 16 + qrow * 4 + r;
          int hid = w * 32 + q * 16 + ln;
          float pi = acc[0][q][rt][r] + bf2f(xg_lds[cc][hid]);
          float pf = acc[1][q][rt][r] + bf2f(xg_lds[cc][256 + hid]);
          float pg = acc[2][q][rt][r] + bf2f(xg_lds[cc][512 + hid]);
          float po = acc[3][q][rt][r] + bf2f(xg_lds[cc][768 + hid]);
          float cn = sigm(pf) * c_st[rt][q][r] + sigm(pi) * tanh_(pg);
          float hn = sigm(po) * tanh_(cn);
          bool skip = mstep && (cg == 0) && (cc == 0);  // the only masked cell: col 0, j==7
          if (!skip) { c_st[rt][q][r] = cn; h_st[rt][q][r] = hn; }
          h_lds[cc][hid] = f2bf(h_st[rt][q][r]);
        }
  }

#pragma unroll
  for (int rt = 0; rt < 2; ++rt)
#pragma unroll
    for (int q = 0; q < 2; ++q)
#pragma unroll
      for (int r = 0; r < 4; ++r) {
        int cc = rt * 16 + qrow * 4 + r;
        int hid = w * 32 + q * 16 + ln;
        out[(long)(cg * 32 + cc) * 512 + d * 256 + hid] = h_st[rt][q][r];
      }
}

extern "C" void kernel_launch(void* const* d_in, const int* in_sizes, int n_in,
                              void* d_out, int out_size, void* d_ws, size_t ws_size,
                              hipStream_t stream) {
  const float* emb  = (const float*)d_in[0];
  const float* wihf = (const float*)d_in[1];
  const float* whhf = (const float*)d_in[2];
  const float* bihf = (const float*)d_in[3];
  const float* bhhf = (const float*)d_in[4];
  const float* wihb = (const float*)d_in[5];
  const float* whhb = (const float*)d_in[6];
  const float* bihb = (const float*)d_in[7];
  const float* bhhb = (const float*)d_in[8];
  const int*   seq  = (const int*)d_in[9];
  float* out = (float*)d_out;

  char* ws = (char*)d_ws;
  // ws layout (bytes): xg 134217728 | X 20971520 | Wih 1310720 | Whh 1048576 | bias 8192
  ushort* xg   = (ushort*)(ws);
  ushort* X    = (ushort*)(ws + 134217728);
  ushort* Wih  = (ushort*)(ws + 155189248);
  ushort* Whh  = (ushort*)(ws + 156499968);
  float*  bias = (float*)(ws + 157548544);

  prep_kernel<<<dim3(1024), dim3(256), 0, stream>>>(emb, wihf, whhf, bihf, bhhf,
                                                    wihb, whhb, bihb, bhhb, seq,
                                                    X, Wih, Whh, bias);
  gemm_xg_kernel<<<dim3(256, 16), dim3(256), 0, stream>>>(X, Wih, bias, xg);
  lstm_kernel<<<dim3(256), dim3(512), 0, stream>>>(xg, Whh, out);
}

// Round 4
// 274.776 us; speedup vs baseline: 1.1897x; 1.1897x over previous
//
#include <hip/hip_runtime.h>

typedef unsigned int uint;
typedef unsigned short ushort;
typedef __attribute__((ext_vector_type(8))) short short8;
typedef __attribute__((ext_vector_type(4))) float f32x4;
typedef __attribute__((ext_vector_type(4))) uint uint4w;

#define T_LEN 32768
#define EMB 300
#define HID 256
#define NCOLS 4096

__device__ __forceinline__ ushort f2bf(float f) {
  uint u = __float_as_uint(f);
  return (ushort)((u + 0x7fffu + ((u >> 16) & 1u)) >> 16);
}
__device__ __forceinline__ float bf2f(ushort u) {
  return __uint_as_float(((uint)u) << 16);
}
__device__ __forceinline__ float sigm(float x) { return 1.f / (1.f + __expf(-x)); }
__device__ __forceinline__ float tanh_(float x) { return 2.f / (1.f + __expf(-2.f * x)) - 1.f; }

__device__ __forceinline__ void gload_lds16(const void* g, void* l) {
  __builtin_amdgcn_global_load_lds((const __attribute__((address_space(1))) void*)g,
                                   (__attribute__((address_space(3))) void*)l, 16, 0, 0);
}

// ---------------- prep: bf16 conversions + embedding gather ----------------
__global__ void prep_kernel(const float* __restrict__ emb,
                            const float* __restrict__ wihf, const float* __restrict__ whhf,
                            const float* __restrict__ bihf, const float* __restrict__ bhhf,
                            const float* __restrict__ wihb, const float* __restrict__ whhb,
                            const float* __restrict__ bihb, const float* __restrict__ bhhb,
                            const int* __restrict__ seq,
                            ushort* __restrict__ X, ushort* __restrict__ Wih,
                            ushort* __restrict__ Whh, float* __restrict__ bias) {
  const int NX = T_LEN * 40;      // 32768 rows x 40 groups of 8 k (K padded to 320)
  const int NWIH = 2048 * 40;
  const int NWHH = 2048 * 32;
  const int NB = 2048;
  const int total = NX + NWIH + NWHH + NB;
  for (int t = blockIdx.x * blockDim.x + threadIdx.x; t < total; t += gridDim.x * blockDim.x) {
    if (t < NX) {
      int r = t / 40, k8 = t % 40, k = k8 * 8;
      int col = r >> 3, j = r & 7;
      int tok = (col == 0) ? j : (col * 8 - 1 + j);   // matches reference idx
      const float* src = emb + (long)seq[tok] * EMB + k;
      alignas(16) ushort tmp[8];
#pragma unroll
      for (int i = 0; i < 8; ++i) tmp[i] = (k + i < EMB) ? f2bf(src[i]) : (ushort)0;
      *(uint4w*)(X + (long)r * 320 + k) = *(const uint4w*)tmp;
    } else if (t < NX + NWIH) {
      int t2 = t - NX;
      int n = t2 / 40, k8 = t2 % 40, k = k8 * 8;
      const float* src = ((n < 1024) ? wihf : wihb) + (long)(n & 1023) * EMB + k;
      alignas(16) ushort tmp[8];
#pragma unroll
      for (int i = 0; i < 8; ++i) tmp[i] = (k + i < EMB) ? f2bf(src[i]) : (ushort)0;
      *(uint4w*)(Wih + (long)n * 320 + k) = *(const uint4w*)tmp;
    } else if (t < NX + NWIH + NWHH) {
      int t3 = t - NX - NWIH;
      int n = t3 / 32, k8 = t3 % 32, k = k8 * 8;
      const float* src = ((n < 1024) ? whhf : whhb) + (long)(n & 1023) * HID + k;
      alignas(16) ushort tmp[8];
#pragma unroll
      for (int i = 0; i < 8; ++i) tmp[i] = f2bf(src[i]);
      *(uint4w*)(Whh + (long)n * 256 + k) = *(const uint4w*)tmp;
    } else {
      int n = t - NX - NWIH - NWHH;
      bias[n] = (n < 1024) ? (bihf[n] + bhhf[n]) : (bihb[n - 1024] + bhhb[n - 1024]);
    }
  }
}

// ---------------- K1: xg = X @ Wih^T + bias  (M=32768,K=320,N=2048) ----------------
__global__ void gemm_xg_kernel(const ushort* __restrict__ X, const ushort* __restrict__ Wih,
                               const float* __restrict__ bias, ushort* __restrict__ xg) {
  __shared__ ushort a_lds[2][128 * 32];
  const int tid = threadIdx.x;
  const int lane = tid & 63, w = tid >> 6;
  const int wr = w >> 1, wc = w & 1;
  const int qrow = lane >> 4, ln = lane & 15;
  const int m0 = blockIdx.x * 128, n0 = blockIdx.y * 128;

  auto stage = [&](int buf, int kt) {
#pragma unroll
    for (int q = 0; q < 2; ++q) {
      int byteoff = w * 2048 + q * 1024 + lane * 16;
      int row = byteoff >> 6, koff = byteoff & 63;
      const char* src = (const char*)X + (long)(m0 + row) * 640 + kt * 64 + koff;
      void* dst = (char*)&a_lds[buf][0] + w * 2048 + q * 1024;  // wave-uniform base
      gload_lds16(src, dst);
    }
  };

  const f32x4 fzero = {0.f, 0.f, 0.f, 0.f};
  f32x4 acc[4][4];
#pragma unroll
  for (int i = 0; i < 4; ++i)
#pragma unroll
    for (int jj = 0; jj < 4; ++jj) acc[i][jj] = fzero;

  stage(0, 0);
#pragma unroll 1
  for (int kt = 0; kt < 10; ++kt) {
    __syncthreads();   // implicit vmcnt(0)+lgkmcnt(0) drain: stage(kt) complete everywhere
    if (kt < 9) stage((kt + 1) & 1, kt + 1);
    const int buf = kt & 1;
    short8 a[4], b[4];
#pragma unroll
    for (int rt = 0; rt < 4; ++rt)
      a[rt] = *(const short8*)&a_lds[buf][(wr * 64 + rt * 16 + ln) * 32 + qrow * 8];
#pragma unroll
    for (int nt = 0; nt < 4; ++nt)
      b[nt] = *(const short8*)(Wih + (long)(n0 + wc * 64 + nt * 16 + ln) * 320 + kt * 32 + qrow * 8);
#pragma unroll
    for (int rt = 0; rt < 4; ++rt)
#pragma unroll
      for (int nt = 0; nt < 4; ++nt)
        acc[rt][nt] = __builtin_amdgcn_mfma_f32_16x16x32_bf16(a[rt], b[nt], acc[rt][nt], 0, 0, 0);
  }

  // epilogue: repack through LDS (reuse a_lds[0]) -> coalesced dwordx4 stores
  ushort* sbuf = &a_lds[0][0];   // 32 x 128 ushort = 8 KB per chunk
  float bv[4];
#pragma unroll
  for (int nt = 0; nt < 4; ++nt) bv[nt] = bias[n0 + wc * 64 + nt * 16 + ln];
#pragma unroll
  for (int R = 0; R < 4; ++R) {
    __syncthreads();   // previous chunk's reads done / k-loop reads done
#pragma unroll
    for (int nt = 0; nt < 4; ++nt)
#pragma unroll
      for (int r = 0; r < 4; ++r)
        sbuf[(wr * 16 + qrow * 4 + r) * 128 + wc * 64 + nt * 16 + ln] = f2bf(acc[R][nt][r] + bv[nt]);
    __syncthreads();
#pragma unroll
    for (int p = 0; p < 2; ++p) {
      int row = p * 16 + (tid >> 4);
      int c0 = (tid & 15) * 8;
      uint4w v = *(uint4w*)&sbuf[row * 128 + c0];
      *(uint4w*)&xg[(long)(m0 + (row >> 4) * 64 + R * 16 + (row & 15)) * 2048 + n0 + c0] = v;
    }
  }
}

// ---------------- K2: fused masked LSTM recurrence, one direction per block ----------------
// grid 256 = {d in 0..1} x {cg in 0..127}; 32 columns per block; 512 threads (8 waves)
__global__ __launch_bounds__(512, 2) void lstm_kernel(const ushort* __restrict__ xg,
                                                      const ushort* __restrict__ Whh,
                                                      float* __restrict__ out) {
  __shared__ ushort h_lds[32][264];          // [col][hid], padded
  __shared__ ushort xg_lds[2][32][1024];     // double-buffered step tile (128 KB)
  const int tid = threadIdx.x;
  const int lane = tid & 63, w = tid >> 6;   // w = hid-slice owner (32 hid per wave)
  const int qrow = lane >> 4, ln = lane & 15;
  const int bid = blockIdx.x;
  const int d = bid >> 7, cg = bid & 127;

  // hoist Whh (loop-invariant per wave) into registers: 64 x short8 = 128 VGPRs
  short8 bw[8][4][2];
#pragma unroll
  for (int ks = 0; ks < 8; ++ks)
#pragma unroll
    for (int g = 0; g < 4; ++g)
#pragma unroll
      for (int q = 0; q < 2; ++q)
        bw[ks][g][q] = *(const short8*)(Whh +
            (long)(d * 1024 + g * 256 + w * 32 + q * 16 + ln) * 256 + ks * 32 + qrow * 8);

  float c_st[2][2][4], h_st[2][2][4];
#pragma unroll
  for (int rt = 0; rt < 2; ++rt)
#pragma unroll
    for (int q = 0; q < 2; ++q)
#pragma unroll
      for (int r = 0; r < 4; ++r) { c_st[rt][q][r] = 0.f; h_st[rt][q][r] = 0.f; }

  auto stage = [&](int buf, int j) {
#pragma unroll
    for (int q = 0; q < 8; ++q) {
      int byteoff = w * 8192 + q * 1024 + lane * 16;
      int cloc = byteoff >> 11, noff = byteoff & 2047;
      const char* src = (const char*)xg + (long)((cg * 32 + cloc) * 8 + j) * 4096 + d * 2048 + noff;
      void* dst = (char*)&xg_lds[0][0][0] + buf * 65536 + w * 8192 + q * 1024;  // wave-uniform
      gload_lds16(src, dst);
    }
  };

  const f32x4 fzero = {0.f, 0.f, 0.f, 0.f};

  stage(0, d ? 7 : 0);

#pragma unroll 1
  for (int it = 0; it < 8; ++it) {
    __syncthreads();   // implicit full drain: stage(it) landed everywhere; h_lds(it-1) visible
    if (it < 7) stage((it + 1) & 1, d ? (6 - it) : (it + 1));  // prefetch stays in flight
    const int buf = it & 1;

    f32x4 acc[4][2][2];  // [gate][q(hid-16-block)][row-tile]
#pragma unroll
    for (int g = 0; g < 4; ++g)
#pragma unroll
      for (int q = 0; q < 2; ++q)
#pragma unroll
        for (int rt = 0; rt < 2; ++rt) acc[g][q][rt] = fzero;

    if (it > 0) {  // h==0 at it==0, skip GEMM
#pragma unroll
      for (int ks = 0; ks < 8; ++ks) {
        short8 a0 = *(const short8*)&h_lds[ln][ks * 32 + qrow * 8];
        short8 a1 = *(const short8*)&h_lds[16 + ln][ks * 32 + qrow * 8];
#pragma unroll
        for (int g = 0; g < 4; ++g)
#pragma unroll
          for (int q = 0; q < 2; ++q) {
            acc[g][q][0] = __builtin_amdgcn_mfma_f32_16x16x32_bf16(a0, bw[ks][g][q], acc[g][q][0], 0, 0, 0);
            acc[g][q][1] = __builtin_amdgcn_mfma_f32_16x16x32_bf16(a1, bw[ks][g][q], acc[g][q][1], 0, 0, 0);
          }
      }
    }
    // LDS-only barrier (do NOT drain vmcnt -> keep xg prefetch in flight):
    asm volatile("s_waitcnt lgkmcnt(0)" ::: "memory");
    __builtin_amdgcn_s_barrier();

    // cell: lane holds all 4 gates of its cells (cc = rt*16+qrow*4+r, hid = w*32+q*16+ln)
    const bool mstep = d ? (it == 0) : (it == 7);
#pragma unroll
    for (int rt = 0; rt < 2; ++rt)
#pragma unroll
      for (int q = 0; q < 2; ++q)
#pragma unroll
        for (int r = 0; r < 4; ++r) {
          int cc = rt * 16 + qrow * 4 + r;
          int hid = w * 32 + q * 16 + ln;
          float pi = acc[0][q][rt][r] + bf2f(xg_lds[buf][cc][hid]);
          float pf = acc[1][q][rt][r] + bf2f(xg_lds[buf][cc][256 + hid]);
          float pg = acc[2][q][rt][r] + bf2f(xg_lds[buf][cc][512 + hid]);
          float po = acc[3][q][rt][r] + bf2f(xg_lds[buf][cc][768 + hid]);
          float cn = sigm(pf) * c_st[rt][q][r] + sigm(pi) * tanh_(pg);
          float hn = sigm(po) * tanh_(cn);
          bool skip = mstep && (cg == 0) && (cc == 0);  // only masked cell: col 0, j==7
          if (!skip) { c_st[rt][q][r] = cn; h_st[rt][q][r] = hn; }
          h_lds[cc][hid] = f2bf(h_st[rt][q][r]);
        }
  }

#pragma unroll
  for (int rt = 0; rt < 2; ++rt)
#pragma unroll
    for (int q = 0; q < 2; ++q)
#pragma unroll
      for (int r = 0; r < 4; ++r) {
        int cc = rt * 16 + qrow * 4 + r;
        int hid = w * 32 + q * 16 + ln;
        out[(long)(cg * 32 + cc) * 512 + d * 256 + hid] = h_st[rt][q][r];
      }
}

extern "C" void kernel_launch(void* const* d_in, const int* in_sizes, int n_in,
                              void* d_out, int out_size, void* d_ws, size_t ws_size,
                              hipStream_t stream) {
  const float* emb  = (const float*)d_in[0];
  const float* wihf = (const float*)d_in[1];
  const float* whhf = (const float*)d_in[2];
  const float* bihf = (const float*)d_in[3];
  const float* bhhf = (const float*)d_in[4];
  const float* wihb = (const float*)d_in[5];
  const float* whhb = (const float*)d_in[6];
  const float* bihb = (const float*)d_in[7];
  const float* bhhb = (const float*)d_in[8];
  const int*   seq  = (const int*)d_in[9];
  float* out = (float*)d_out;

  char* ws = (char*)d_ws;
  // ws layout (bytes): xg 134217728 | X 20971520 | Wih 1310720 | Whh 1048576 | bias 8192
  ushort* xg   = (ushort*)(ws);
  ushort* X    = (ushort*)(ws + 134217728);
  ushort* Wih  = (ushort*)(ws + 155189248);
  ushort* Whh  = (ushort*)(ws + 156499968);
  float*  bias = (float*)(ws + 157548544);

  prep_kernel<<<dim3(1024), dim3(256), 0, stream>>>(emb, wihf, whhf, bihf, bhhf,
                                                    wihb, whhb, bihb, bhhb, seq,
                                                    X, Wih, Whh, bias);
  gemm_xg_kernel<<<dim3(256, 16), dim3(256), 0, stream>>>(X, Wih, bias, xg);
  lstm_kernel<<<dim3(256), dim3(512), 0, stream>>>(xg, Whh, out);
}